// Round 1
// baseline (51.260 us; speedup 1.0000x reference)
//
#include <hip/hip_runtime.h>

#define NB 128
#define NC 16
#define NT 16384
#define NW 4096

__global__ __launch_bounds__(256) void rww_kernel(
    const float* __restrict__ x,
    const int* __restrict__ window_starts,
    const int* __restrict__ new_len,
    float* __restrict__ out)
{
    const int b = blockIdx.y;
    const int t = blockIdx.x * 256 + threadIdx.x;

    const int s  = window_starts[b];
    const int nl = new_len[b];
    const float sf  = (float)s;
    const float nlf = (float)nl;
    const float den = fmaxf(nlf - 1.0f, 1.0f);
    const int   L   = NT + nl - NW;
    const float Lf  = (float)L;

    // Stage 2 query position: q = t*(L-1)/(T-1)  (left-to-right like the ref)
    float qpos = (float)t * (Lf - 1.0f) / (float)(NT - 1);
    int   qlo  = (int)floorf(qpos);
    int   qhi  = min(qlo + 1, L - 1);
    float qf   = qpos - (float)qlo;

    // Stage 1 source position for a warped index j
    int lo0, hi0, lo1, hi1;
    float f0, f1;
    {
        float jf = (float)qlo;
        float pos;
        if (jf >= sf + nlf)      pos = jf - nlf + (float)NW;          // after window
        else if (jf >= sf)       pos = sf + (jf - sf) * (float)(NW - 1) / den; // in window
        else                     pos = jf;                            // before window
        pos = fminf(fmaxf(pos, 0.0f), (float)(NT - 1));
        lo0 = (int)floorf(pos);
        hi0 = min(lo0 + 1, NT - 1);
        f0  = pos - (float)lo0;
    }
    {
        float jf = (float)qhi;
        float pos;
        if (jf >= sf + nlf)      pos = jf - nlf + (float)NW;
        else if (jf >= sf)       pos = sf + (jf - sf) * (float)(NW - 1) / den;
        else                     pos = jf;
        pos = fminf(fmaxf(pos, 0.0f), (float)(NT - 1));
        lo1 = (int)floorf(pos);
        hi1 = min(lo1 + 1, NT - 1);
        f1  = pos - (float)lo1;
    }

    const float* xb = x   + (size_t)b * NC * NT;
    float*       ob = out + (size_t)b * NC * NT;

    const float g0 = 1.0f - f0;
    const float g1 = 1.0f - f1;
    const float gq = 1.0f - qf;

    #pragma unroll
    for (int c = 0; c < NC; ++c) {
        const float* xc = xb + c * NT;
        float a0 = xc[lo0];
        float b0 = xc[hi0];
        float a1 = xc[lo1];
        float b1 = xc[hi1];
        float v0 = a0 * g0 + b0 * f0;   // warped[qlo]
        float v1 = a1 * g1 + b1 * f1;   // warped[qhi]
        ob[c * NT + t] = v0 * gq + v1 * qf;
    }
}

extern "C" void kernel_launch(void* const* d_in, const int* in_sizes, int n_in,
                              void* d_out, int out_size, void* d_ws, size_t ws_size,
                              hipStream_t stream) {
    const float* x  = (const float*)d_in[0];
    const int*   ws = (const int*)d_in[1];
    const int*   nl = (const int*)d_in[2];
    float*       out = (float*)d_out;

    dim3 grid(NT / 256, NB);
    dim3 block(256);
    rww_kernel<<<grid, block, 0, stream>>>(x, ws, nl, out);
}

// Round 2
// 50.792 us; speedup vs baseline: 1.0092x; 1.0092x over previous
//
#include <hip/hip_runtime.h>

#define NB 128
#define NC 16
#define NT 16384
#define NW 4096

__global__ __launch_bounds__(256) void rww_kernel(
    const float* __restrict__ x,
    const int* __restrict__ window_starts,
    const int* __restrict__ new_len,
    float* __restrict__ out)
{
    const int b = blockIdx.y;
    const int t = blockIdx.x * 256 + threadIdx.x;

    const int s  = window_starts[b];
    const int nl = new_len[b];
    const float sf  = (float)s;
    const float nlf = (float)nl;
    const float den = fmaxf(nlf - 1.0f, 1.0f);
    const int   L   = NT + nl - NW;
    const float Lf  = (float)L;

    // Stage 2 query position: q = t*(L-1)/(T-1)
    float qpos = (float)t * (Lf - 1.0f) / (float)(NT - 1);
    int   qlo  = (int)floorf(qpos);
    int   qhi  = min(qlo + 1, L - 1);
    float qf   = qpos - (float)qlo;

    // Stage 1 source positions for warped indices qlo, qhi
    int lo0, hi0, lo1, hi1;
    float f0, f1;
    {
        float jf = (float)qlo;
        float pos;
        if (jf >= sf + nlf)      pos = jf - nlf + (float)NW;
        else if (jf >= sf)       pos = sf + (jf - sf) * (float)(NW - 1) / den;
        else                     pos = jf;
        pos = fminf(fmaxf(pos, 0.0f), (float)(NT - 1));
        lo0 = (int)floorf(pos);
        hi0 = min(lo0 + 1, NT - 1);
        f0  = pos - (float)lo0;
    }
    {
        float jf = (float)qhi;
        float pos;
        if (jf >= sf + nlf)      pos = jf - nlf + (float)NW;
        else if (jf >= sf)       pos = sf + (jf - sf) * (float)(NW - 1) / den;
        else                     pos = jf;
        pos = fminf(fmaxf(pos, 0.0f), (float)(NT - 1));
        lo1 = (int)floorf(pos);
        hi1 = min(lo1 + 1, NT - 1);
        f1  = pos - (float)lo1;
    }

    const float g0 = 1.0f - f0;
    const float g1 = 1.0f - f1;
    const float gq = 1.0f - qf;

    // All four gather indices lie in [lo0, lo0+4]  (pos step <= 2.0005).
    // base = 4-aligned window of 8 floats covering them, clamped in-row.
    int base = lo0 & ~3;
    if (base > NT - 8) base = NT - 8;

    // 8 per-t weights, shared across all channels:
    // out = sum_k w[k] * x[c][base+k]
    float w[8];
    #pragma unroll
    for (int k = 0; k < 8; ++k) {
        const int kk = base + k;
        float w0 = 0.0f, w1 = 0.0f;
        if (kk == lo0) w0 += g0;
        if (kk == hi0) w0 += f0;
        if (kk == lo1) w1 += g1;
        if (kk == hi1) w1 += f1;
        w[k] = gq * w0 + qf * w1;
    }

    const float* xb = x   + (size_t)b * NC * NT;
    float*       ob = out + (size_t)b * NC * NT;

    #pragma unroll
    for (int c = 0; c < NC; ++c) {
        const float* xc = xb + c * NT;
        const float4 va = *(const float4*)(xc + base);
        const float4 vb = *(const float4*)(xc + base + 4);
        float r;
        r  = va.x * w[0];
        r += va.y * w[1];
        r += va.z * w[2];
        r += va.w * w[3];
        r += vb.x * w[4];
        r += vb.y * w[5];
        r += vb.z * w[6];
        r += vb.w * w[7];
        ob[c * NT + t] = r;
    }
}

extern "C" void kernel_launch(void* const* d_in, const int* in_sizes, int n_in,
                              void* d_out, int out_size, void* d_ws, size_t ws_size,
                              hipStream_t stream) {
    const float* x  = (const float*)d_in[0];
    const int*   ws = (const int*)d_in[1];
    const int*   nl = (const int*)d_in[2];
    float*       out = (float*)d_out;

    dim3 grid(NT / 256, NB);
    dim3 block(256);
    rww_kernel<<<grid, block, 0, stream>>>(x, ws, nl, out);
}

// Round 4
// 48.509 us; speedup vs baseline: 1.0567x; 1.0471x over previous
//
#include <hip/hip_runtime.h>

#define NB 128
#define NC 16
#define NT 16384
#define NW 4096

typedef float f32x4 __attribute__((ext_vector_type(4)));

// Each thread computes 4 consecutive outputs t0..t0+3 for all 16 channels.
// All source samples needed by the 4 outputs lie in one 16-float aligned
// window (positions are monotone, slope <= 1.75 per t, plus 4-tap spread).
__global__ __launch_bounds__(256) void rww_kernel(
    const float* __restrict__ x,
    const int* __restrict__ window_starts,
    const int* __restrict__ new_len,
    float* __restrict__ out)
{
    const int b  = blockIdx.y;
    const int t0 = (blockIdx.x * 256 + threadIdx.x) * 4;

    const int s  = window_starts[b];
    const int nl = new_len[b];
    const float sf  = (float)s;
    const float nlf = (float)nl;
    const float den = fmaxf(nlf - 1.0f, 1.0f);
    const int   L   = NT + nl - NW;
    const float Lf  = (float)L;

    int   lo0[4], hi0[4], lo1[4], hi1[4];
    float f0[4], f1[4], qf[4];

    #pragma unroll
    for (int i = 0; i < 4; ++i) {
        const int t = t0 + i;
        float qpos = (float)t * (Lf - 1.0f) / (float)(NT - 1);
        int   ql   = (int)floorf(qpos);
        int   qh   = min(ql + 1, L - 1);
        qf[i]      = qpos - (float)ql;

        {   // stage-1 position for warped index ql
            float jf = (float)ql;
            float pos;
            if (jf >= sf + nlf)      pos = jf - nlf + (float)NW;
            else if (jf >= sf)       pos = sf + (jf - sf) * (float)(NW - 1) / den;
            else                     pos = jf;
            pos = fminf(fmaxf(pos, 0.0f), (float)(NT - 1));
            lo0[i] = (int)floorf(pos);
            hi0[i] = min(lo0[i] + 1, NT - 1);
            f0[i]  = pos - (float)lo0[i];
        }
        {   // stage-1 position for warped index qh
            float jf = (float)qh;
            float pos;
            if (jf >= sf + nlf)      pos = jf - nlf + (float)NW;
            else if (jf >= sf)       pos = sf + (jf - sf) * (float)(NW - 1) / den;
            else                     pos = jf;
            pos = fminf(fmaxf(pos, 0.0f), (float)(NT - 1));
            lo1[i] = (int)floorf(pos);
            hi1[i] = min(lo1[i] + 1, NT - 1);
            f1[i]  = pos - (float)lo1[i];
        }
    }

    // Aligned 16-float window covering all 16 tap indices.
    // lo0[] is nondecreasing; all taps are in [lo0[0], lo0[0]+12].
    int base = lo0[0] & ~3;
    base = min(base, NT - 16);

    // Per-t 16-wide weight vectors over the window (compile-time indices only).
    float w[4][16];
    #pragma unroll
    for (int i = 0; i < 4; ++i) {
        const float g0 = 1.0f - f0[i];
        const float g1 = 1.0f - f1[i];
        const float gq = 1.0f - qf[i];
        #pragma unroll
        for (int k = 0; k < 16; ++k) {
            const int kk = base + k;
            float w0 = (kk == lo0[i] ? g0 : 0.0f) + (kk == hi0[i] ? f0[i] : 0.0f);
            float w1 = (kk == lo1[i] ? g1 : 0.0f) + (kk == hi1[i] ? f1[i] : 0.0f);
            w[i][k] = gq * w0 + qf[i] * w1;
        }
    }

    const float* xb = x   + (size_t)b * NC * NT;
    float*       ob = out + (size_t)b * NC * NT;

    #pragma unroll 4
    for (int c = 0; c < NC; ++c) {
        const float* xc = xb + c * NT + base;
        const f32x4 v0 = *(const f32x4*)(xc);
        const f32x4 v1 = *(const f32x4*)(xc + 4);
        const f32x4 v2 = *(const f32x4*)(xc + 8);
        const f32x4 v3 = *(const f32x4*)(xc + 12);
        const float win[16] = {v0.x, v0.y, v0.z, v0.w,
                               v1.x, v1.y, v1.z, v1.w,
                               v2.x, v2.y, v2.z, v2.w,
                               v3.x, v3.y, v3.z, v3.w};
        f32x4 r;
        #pragma unroll
        for (int i = 0; i < 4; ++i) {
            float acc = 0.0f;
            #pragma unroll
            for (int k = 0; k < 16; ++k)
                acc += w[i][k] * win[k];
            r[i] = acc;
        }
        __builtin_nontemporal_store(r, (f32x4*)(ob + c * NT + t0));
    }
}

extern "C" void kernel_launch(void* const* d_in, const int* in_sizes, int n_in,
                              void* d_out, int out_size, void* d_ws, size_t ws_size,
                              hipStream_t stream) {
    const float* x   = (const float*)d_in[0];
    const int*   ws  = (const int*)d_in[1];
    const int*   nl  = (const int*)d_in[2];
    float*       out = (float*)d_out;

    dim3 grid(NT / (256 * 4), NB);
    dim3 block(256);
    rww_kernel<<<grid, block, 0, stream>>>(x, ws, nl, out);
}